// Round 22
// baseline (331.578 us; speedup 1.0000x reference)
//
#include <hip/hip_runtime.h>
#include <hip/hip_bf16.h>

#define T_DIM 4096
#define B_DIM 32
#define I_DIM 512
#define O_DIM 512
#define M_DIM (T_DIM * B_DIM)   // 131072
#define PARAM 0.1f
#define ISCALE 1.1111112f       // 1/(1-p)

#define STRIP 32
#define TAPS 8                  // p^8 = 1e-8 << bf16 eps

#define BM 128
#define BN 128
#define BK 64
#define NK (I_DIM / BK)         // 8

typedef __attribute__((ext_vector_type(8))) short bf16x8;
typedef __attribute__((ext_vector_type(4))) float f32x4;

__device__ __forceinline__ unsigned short f2bf(float f) {
    union { __hip_bfloat16 b; unsigned short u; } cv;
    cv.b = __float2bfloat16(f);
    return cv.u;
}

// --- EMA over raw X (linearity: EMA(XW+b) = EMA(X)W + s[t]*bias). Strip-
// parallel, TAPS warm-up reads raw X; bf16 output compacted into d_ws.
// Blocks 0..255 ALSO convert W fp32->bf16 (folded wcvt; xema completes before
// gemm on the same stream). Near its HBM roofline (~80us). ---
__global__ __launch_bounds__(256) void xema_kernel(const float* __restrict__ X,
                                                   const float* __restrict__ W,
                                                   unsigned short* __restrict__ Xv,
                                                   unsigned short* __restrict__ Wb) {
    if (blockIdx.x < 256) {
        const int i = (blockIdx.x * 256 + threadIdx.x) * 4;
        f32x4 v = *(const f32x4*)(W + i);
        ushort4 o;
        o.x = f2bf(v[0]); o.y = f2bf(v[1]); o.z = f2bf(v[2]); o.w = f2bf(v[3]);
        *(ushort4*)(Wb + i) = o;
    }

    const int s   = blockIdx.x >> 4;                 // strip 0..127
    const int blk = blockIdx.x & 15;
    const int col = (blk * 256 + threadIdx.x) * 4;
    const int t0  = s * STRIP;
    const int b   = col >> 9;
    const int o   = col & 511;

    const float* xin = X + (size_t)t0 * 16384 + col;
    unsigned short* xout = Xv + (size_t)(t0 * 32 + b) * 512 + o;

    f32x4 v = {0.f, 0.f, 0.f, 0.f};
    if (s > 0) {
        const float* w = xin - (size_t)TAPS * 16384;
        #pragma unroll
        for (int j = 0; j < TAPS; ++j)
            v = PARAM * v + *(const f32x4*)(w + (size_t)j * 16384);
    }

    f32x4 bufA[4], bufB[4];
    #pragma unroll
    for (int j = 0; j < 4; ++j) bufA[j] = *(const f32x4*)(xin + (size_t)j * 16384);

    #pragma unroll
    for (int i = 0; i < STRIP; i += 8) {
        #pragma unroll
        for (int j = 0; j < 4; ++j)
            bufB[j] = *(const f32x4*)(xin + (size_t)(i + 4 + j) * 16384);
        #pragma unroll
        for (int j = 0; j < 4; ++j) {
            v = PARAM * v + bufA[j];
            ushort4 pk; pk.x = f2bf(v[0]); pk.y = f2bf(v[1]); pk.z = f2bf(v[2]); pk.w = f2bf(v[3]);
            *(ushort4*)(xout + (size_t)(i + j) * 16384) = pk;
        }
        if (i + 8 < STRIP) {
            #pragma unroll
            for (int j = 0; j < 4; ++j)
                bufA[j] = *(const f32x4*)(xin + (size_t)(i + 8 + j) * 16384);
        }
        #pragma unroll
        for (int j = 0; j < 4; ++j) {
            v = PARAM * v + bufB[j];
            ushort4 pk; pk.x = f2bf(v[0]); pk.y = f2bf(v[1]); pk.z = f2bf(v[2]); pk.w = f2bf(v[3]);
            *(ushort4*)(xout + (size_t)(i + 4 + j) * 16384) = pk;
        }
    }
}

// --- GEMM: persistent-segment variant of the best structure (R13/R21 inner
// loop, verified byte-identical). Grid 1024 = one block per mt (4 blk/CU,
// fully resident). Each block loops 4 segments (bn = 0..3) over its 128-row
// A panel: 32 K-steps/block instead of 8 -> block-level transients amortized
// 4x, blocks drift out of phase over the long loop, and each segment's Y
// stores fire BETWEEN segments, overlapping the next segment's staging within
// the block. A re-staged per seg from L2 (per-XCD concurrent A = 4MB ~ L2,
// R14-verified); W (512KB) L2-hot. Pre-swizzled gload_lds (involution
// c^(r&7)); conflict-free swizzled ds_read; swapped-operand MFMA -> Y^T
// frags -> float4 epilogue. ---
__global__ __launch_bounds__(256, 4) void gemm_kernel(const unsigned short* __restrict__ Xv,
                                                      const unsigned short* __restrict__ Wb,
                                                      const float* __restrict__ bias,
                                                      float* __restrict__ Y) {
    __shared__ __align__(16) short As[BM * BK];   // 16 KB
    __shared__ __align__(16) short Bs[BN * BK];   // 16 KB

    const int tid  = threadIdx.x;
    const int lane = tid & 63;
    const int wave = tid >> 6;        // 0..3
    const int wm   = wave >> 1;       // 0..1
    const int wn   = wave & 1;        // 0..1

    // 1024 blocks: xcd = bid&7; 128 consecutive mt per XCD.
    const int bid  = blockIdx.x;
    const int mt   = (bid & 7) * 128 + (bid >> 3);   // 0..1023
    const int row0 = mt * BM;

    // Staging: 16B chunks, 8 per 128B row; 4 sets of 32 rows. r&7 = (tid>>3)&7
    // for every set -> swizzled source chunk cs is per-thread constant.
    const int cs = (tid & 7) ^ ((tid >> 3) & 7);
    const unsigned short* aSrc  = Xv + (size_t)(row0 + (tid >> 3)) * 512 + cs * 8;
    const unsigned short* bSrc0 = Wb + (size_t)(tid >> 3) * 512 + cs * 8;

    for (int seg = 0; seg < 4; ++seg) {
        const int col0 = seg * BN;
        const unsigned short* bSrc = bSrc0 + (size_t)col0 * 512;

        f32x4 acc[4][4] = {};   // [mf][nf], swapped-operand: reg j = 4 consecutive Y-cols

        for (int ks = 0; ks < NK; ++ks) {
            const int k0 = ks * BK;
            #pragma unroll
            for (int s_ = 0; s_ < 4; ++s_)
                __builtin_amdgcn_global_load_lds(
                    (const __attribute__((address_space(1))) unsigned int*)(aSrc + (size_t)s_ * 32 * 512 + k0),
                    (__attribute__((address_space(3))) unsigned int*)(As + (s_ * 256 + tid) * 8),
                    16, 0, 0);
            #pragma unroll
            for (int s_ = 0; s_ < 4; ++s_)
                __builtin_amdgcn_global_load_lds(
                    (const __attribute__((address_space(1))) unsigned int*)(bSrc + (size_t)s_ * 32 * 512 + k0),
                    (__attribute__((address_space(3))) unsigned int*)(Bs + (s_ * 256 + tid) * 8),
                    16, 0, 0);
            __syncthreads();

            #pragma unroll
            for (int kk = 0; kk < 2; ++kk) {
                const int cc = kk * 4 + (lane >> 4);
                bf16x8 a_[4], b_[4];
                #pragma unroll
                for (int mf = 0; mf < 4; ++mf) {
                    const int r = wm * 64 + mf * 16 + (lane & 15);
                    a_[mf] = *(const bf16x8*)((const char*)As + r * 128 + ((cc ^ (r & 7)) << 4));
                }
                #pragma unroll
                for (int nf = 0; nf < 4; ++nf) {
                    const int r = wn * 64 + nf * 16 + (lane & 15);
                    b_[nf] = *(const bf16x8*)((const char*)Bs + r * 128 + ((cc ^ (r & 7)) << 4));
                }
                #pragma unroll
                for (int mf = 0; mf < 4; ++mf)
                    #pragma unroll
                    for (int nf = 0; nf < 4; ++nf)
                        acc[mf][nf] = __builtin_amdgcn_mfma_f32_16x16x32_bf16(
                            b_[nf], a_[mf], acc[mf][nf], 0, 0, 0);   // swapped -> Y^T frag
            }
            __syncthreads();
        }

        // Segment epilogue: Y = acc + s[t]*bias, float4 stores. Fire-and-forget:
        // overlaps the next segment's staging (no barrier between).
        float sc4[2];
        #pragma unroll
        for (int tt = 0; tt < 2; ++tt) {
            const int t_ = ((row0 + wm * 64) >> 5) + tt;
            sc4[tt] = (1.0f - __expf(-2.3025851f * (float)(t_ + 1))) * ISCALE;
        }
        f32x4 bvv[4];
        #pragma unroll
        for (int nf = 0; nf < 4; ++nf)
            bvv[nf] = *(const f32x4*)(bias + col0 + wn * 64 + nf * 16 + ((lane >> 4) << 2));

        #pragma unroll
        for (int mf = 0; mf < 4; ++mf) {
            const int grow = row0 + wm * 64 + mf * 16 + (lane & 15);
            const float sc = sc4[mf >> 1];
            #pragma unroll
            for (int nf = 0; nf < 4; ++nf) {
                const int gcol = col0 + wn * 64 + nf * 16 + ((lane >> 4) << 2);
                f32x4 out;
                #pragma unroll
                for (int e = 0; e < 4; ++e) out[e] = acc[mf][nf][e] + sc * bvv[nf][e];
                *(f32x4*)(Y + (size_t)grow * O_DIM + gcol) = out;
            }
        }
    }
}

extern "C" void kernel_launch(void* const* d_in, const int* in_sizes, int n_in,
                              void* d_out, int out_size, void* d_ws, size_t ws_size,
                              hipStream_t stream) {
    const float* X    = (const float*)d_in[0];
    const float* W    = (const float*)d_in[1];
    const float* bias = (const float*)d_in[2];
    float* Y = (float*)d_out;
    unsigned short* Wb = (unsigned short*)d_ws;                       // 512 KB
    unsigned short* Xv = (unsigned short*)((char*)d_ws + (1 << 20));  // 134 MB

    xema_kernel<<<dim3((T_DIM / STRIP) * 16), dim3(256), 0, stream>>>(X, W, Xv, Wb);
    gemm_kernel<<<dim3(M_DIM / BM), dim3(256), 0, stream>>>(Xv, Wb, bias, Y);
}

// Round 23
// 227.007 us; speedup vs baseline: 1.4607x; 1.4607x over previous
//
#include <hip/hip_runtime.h>
#include <hip/hip_bf16.h>

#define T_DIM 4096
#define B_DIM 32
#define I_DIM 512
#define O_DIM 512
#define M_DIM (T_DIM * B_DIM)   // 131072
#define PARAM 0.1f
#define ISCALE 1.1111112f       // 1/(1-p)

#define STRIP 32
#define TAPS 8                  // p^8 = 1e-8 << bf16 eps

#define BM 128
#define BN 128
#define BK 64
#define NK (I_DIM / BK)         // 8

typedef __attribute__((ext_vector_type(8))) short bf16x8;
typedef __attribute__((ext_vector_type(4))) float f32x4;

__device__ __forceinline__ unsigned short f2bf(float f) {
    union { __hip_bfloat16 b; unsigned short u; } cv;
    cv.b = __float2bfloat16(f);
    return cv.u;
}

// --- EMA over raw X (linearity: EMA(XW+b) = EMA(X)W + s[t]*bias). Strip-
// parallel, TAPS warm-up reads raw X; bf16 output compacted into d_ws.
// Blocks 0..255 ALSO convert W fp32->bf16 (folded wcvt: xema fully completes
// before gemm on the same stream, so Wb is ready when gemm starts).
// At ~95% of its HBM roofline (~470MB moved). ---
__global__ __launch_bounds__(256) void xema_kernel(const float* __restrict__ X,
                                                   const float* __restrict__ W,
                                                   unsigned short* __restrict__ Xv,
                                                   unsigned short* __restrict__ Wb) {
    if (blockIdx.x < 256) {
        const int i = (blockIdx.x * 256 + threadIdx.x) * 4;
        f32x4 v = *(const f32x4*)(W + i);
        ushort4 o;
        o.x = f2bf(v[0]); o.y = f2bf(v[1]); o.z = f2bf(v[2]); o.w = f2bf(v[3]);
        *(ushort4*)(Wb + i) = o;
    }

    const int s   = blockIdx.x >> 4;                 // strip 0..127
    const int blk = blockIdx.x & 15;
    const int col = (blk * 256 + threadIdx.x) * 4;
    const int t0  = s * STRIP;
    const int b   = col >> 9;
    const int o   = col & 511;

    const float* xin = X + (size_t)t0 * 16384 + col;
    unsigned short* xout = Xv + (size_t)(t0 * 32 + b) * 512 + o;

    f32x4 v = {0.f, 0.f, 0.f, 0.f};
    if (s > 0) {
        const float* w = xin - (size_t)TAPS * 16384;
        #pragma unroll
        for (int j = 0; j < TAPS; ++j)
            v = PARAM * v + *(const f32x4*)(w + (size_t)j * 16384);
    }

    f32x4 bufA[4], bufB[4];
    #pragma unroll
    for (int j = 0; j < 4; ++j) bufA[j] = *(const f32x4*)(xin + (size_t)j * 16384);

    #pragma unroll
    for (int i = 0; i < STRIP; i += 8) {
        #pragma unroll
        for (int j = 0; j < 4; ++j)
            bufB[j] = *(const f32x4*)(xin + (size_t)(i + 4 + j) * 16384);
        #pragma unroll
        for (int j = 0; j < 4; ++j) {
            v = PARAM * v + bufA[j];
            ushort4 pk; pk.x = f2bf(v[0]); pk.y = f2bf(v[1]); pk.z = f2bf(v[2]); pk.w = f2bf(v[3]);
            *(ushort4*)(xout + (size_t)(i + j) * 16384) = pk;
        }
        if (i + 8 < STRIP) {
            #pragma unroll
            for (int j = 0; j < 4; ++j)
                bufA[j] = *(const f32x4*)(xin + (size_t)(i + 8 + j) * 16384);
        }
        #pragma unroll
        for (int j = 0; j < 4; ++j) {
            v = PARAM * v + bufB[j];
            ushort4 pk; pk.x = f2bf(v[0]); pk.y = f2bf(v[1]); pk.z = f2bf(v[2]); pk.w = f2bf(v[3]);
            *(ushort4*)(xout + (size_t)(i + 4 + j) * 16384) = pk;
        }
    }
}

// --- GEMM: best-measured structure (R13/R18/R21, 226.8us total). m97 replica:
// 256 thr / 4 waves, 128x128 tile, BK=64, wave-tile 64x64, single-buffer 32KB
// LDS -> 4 blocks/CU; pre-swizzled gload_lds staging (involution c^(r&7));
// conflict-free swizzled ds_read; swapped-operand MFMA -> Y^T frags -> float4
// epilogue; entry stagger (neutral-measured, harmless). Latency-bound plateau
// for NK=8 at ~145us across 10 schedule variants — structural for this shape
// at HIP source level (deeper pipelining requires inline-asm K-loops; register
// pipelines are rematerialized by hipcc: VGPR-counter proof x4). ---
__global__ __launch_bounds__(256, 4) void gemm_kernel(const unsigned short* __restrict__ Xv,
                                                      const unsigned short* __restrict__ Wb,
                                                      const float* __restrict__ bias,
                                                      float* __restrict__ Y) {
    __shared__ __align__(16) short As[BM * BK];   // 16 KB
    __shared__ __align__(16) short Bs[BN * BK];   // 16 KB

    switch ((blockIdx.x >> 8) & 3) {
        case 1: __builtin_amdgcn_s_sleep(8);  break;
        case 2: __builtin_amdgcn_s_sleep(16); break;
        case 3: __builtin_amdgcn_s_sleep(24); break;
        default: break;
    }

    const int tid  = threadIdx.x;
    const int lane = tid & 63;
    const int wave = tid >> 6;        // 0..3
    const int wm   = wave >> 1;       // 0..1
    const int wn   = wave & 1;        // 0..1

    // 4096 blocks: xcd = bid&7; all 4 bn of one mt adjacent per XCD -> A panel
    // HBM-fetched once, L2-served 4x; W (512KB) stays L2-hot.
    const int bid = blockIdx.x;
    const int j   = bid >> 3;                     // 0..511
    const int bn  = j & 3;
    const int mt  = (bid & 7) * 128 + (j >> 2);   // 0..1023
    const int row0 = mt * BM;
    const int col0 = bn * BN;

    const int cs = (tid & 7) ^ ((tid >> 3) & 7);
    const unsigned short* aSrc = Xv + (size_t)(row0 + (tid >> 3)) * 512 + cs * 8;
    const unsigned short* bSrc = Wb + (size_t)(col0 + (tid >> 3)) * 512 + cs * 8;

    f32x4 acc[4][4] = {};   // [mf][nf], swapped-operand: reg j = 4 consecutive Y-cols

    for (int ks = 0; ks < NK; ++ks) {
        const int k0 = ks * BK;
        #pragma unroll
        for (int s_ = 0; s_ < 4; ++s_)
            __builtin_amdgcn_global_load_lds(
                (const __attribute__((address_space(1))) unsigned int*)(aSrc + (size_t)s_ * 32 * 512 + k0),
                (__attribute__((address_space(3))) unsigned int*)(As + (s_ * 256 + tid) * 8),
                16, 0, 0);
        #pragma unroll
        for (int s_ = 0; s_ < 4; ++s_)
            __builtin_amdgcn_global_load_lds(
                (const __attribute__((address_space(1))) unsigned int*)(bSrc + (size_t)s_ * 32 * 512 + k0),
                (__attribute__((address_space(3))) unsigned int*)(Bs + (s_ * 256 + tid) * 8),
                16, 0, 0);
        __syncthreads();

        #pragma unroll
        for (int kk = 0; kk < 2; ++kk) {
            const int cc = kk * 4 + (lane >> 4);
            bf16x8 a_[4], b_[4];
            #pragma unroll
            for (int mf = 0; mf < 4; ++mf) {
                const int r = wm * 64 + mf * 16 + (lane & 15);
                a_[mf] = *(const bf16x8*)((const char*)As + r * 128 + ((cc ^ (r & 7)) << 4));
            }
            #pragma unroll
            for (int nf = 0; nf < 4; ++nf) {
                const int r = wn * 64 + nf * 16 + (lane & 15);
                b_[nf] = *(const bf16x8*)((const char*)Bs + r * 128 + ((cc ^ (r & 7)) << 4));
            }
            #pragma unroll
            for (int mf = 0; mf < 4; ++mf)
                #pragma unroll
                for (int nf = 0; nf < 4; ++nf)
                    acc[mf][nf] = __builtin_amdgcn_mfma_f32_16x16x32_bf16(
                        b_[nf], a_[mf], acc[mf][nf], 0, 0, 0);   // swapped -> Y^T frag
        }
        __syncthreads();
    }

    // Epilogue: Y = acc + s[t]*bias, float4 stores (Y^T frag: reg j = 4 cols).
    float sc4[2];
    #pragma unroll
    for (int tt = 0; tt < 2; ++tt) {
        const int t_ = ((row0 + wm * 64) >> 5) + tt;
        sc4[tt] = (1.0f - __expf(-2.3025851f * (float)(t_ + 1))) * ISCALE;
    }
    f32x4 bvv[4];
    #pragma unroll
    for (int nf = 0; nf < 4; ++nf)
        bvv[nf] = *(const f32x4*)(bias + col0 + wn * 64 + nf * 16 + ((lane >> 4) << 2));

    #pragma unroll
    for (int mf = 0; mf < 4; ++mf) {
        const int grow = row0 + wm * 64 + mf * 16 + (lane & 15);
        const float sc = sc4[mf >> 1];
        #pragma unroll
        for (int nf = 0; nf < 4; ++nf) {
            const int gcol = col0 + wn * 64 + nf * 16 + ((lane >> 4) << 2);
            f32x4 out;
            #pragma unroll
            for (int e = 0; e < 4; ++e) out[e] = acc[mf][nf][e] + sc * bvv[nf][e];
            *(f32x4*)(Y + (size_t)grow * O_DIM + gcol) = out;
        }
    }
}

extern "C" void kernel_launch(void* const* d_in, const int* in_sizes, int n_in,
                              void* d_out, int out_size, void* d_ws, size_t ws_size,
                              hipStream_t stream) {
    const float* X    = (const float*)d_in[0];
    const float* W    = (const float*)d_in[1];
    const float* bias = (const float*)d_in[2];
    float* Y = (float*)d_out;
    unsigned short* Wb = (unsigned short*)d_ws;                       // 512 KB
    unsigned short* Xv = (unsigned short*)((char*)d_ws + (1 << 20));  // 134 MB

    xema_kernel<<<dim3((T_DIM / STRIP) * 16), dim3(256), 0, stream>>>(X, W, Xv, Wb);
    gemm_kernel<<<dim3((M_DIM / BM) * (O_DIM / BN)), dim3(256), 0, stream>>>(Xv, Wb, bias, Y);
}